// Round 3
// baseline (106.589 us; speedup 1.0000x reference)
//
#include <hip/hip_runtime.h>
#include <hip/hip_bf16.h>
#include <math.h>

typedef _Float16 half8_t __attribute__((ext_vector_type(8)));
typedef _Float16 half4_t __attribute__((ext_vector_type(4)));
typedef float floatx4 __attribute__((ext_vector_type(4)));

#define TILES_PER_BLOCK 4

// ---------------------------------------------------------------------------
// K0: repack fp32 weights (K x N row-major) into fp16 MFMA B-fragment layout:
// dst[((nt*KS+ks)*64 + lane)*8 + j] = (half) W[ks*32 + (lane>>4)*8 + j][nt*16 + (lane&15)]
// zero-padded for k >= K or col >= N.  One merged launch for W1/W2/W3.
// ---------------------------------------------------------------------------
__device__ __forceinline__ void prep_body(const float* __restrict__ W,
                                          _Float16* __restrict__ dst,
                                          int K, int N, int KS, int b) {
    int ks   = b % KS;
    int nt   = b / KS;
    int lane = threadIdx.x;         // 64
    int col  = nt * 16 + (lane & 15);
    int kbase = ks * 32 + ((lane >> 4) << 3);
    half8_t v;
#pragma unroll
    for (int j = 0; j < 8; ++j) {
        int k = kbase + j;
        float x = (k < K && col < N) ? W[(size_t)k * N + col] : 0.f;
        v[j] = (_Float16)x;
    }
    *(half8_t*)(dst + (size_t)(b * 64 + lane) * 8) = v;
}

__global__ void prep_all(const float* __restrict__ W1, const float* __restrict__ W2,
                         const float* __restrict__ W3,
                         _Float16* __restrict__ w1f, _Float16* __restrict__ w2f,
                         _Float16* __restrict__ w3f) {
    int b = blockIdx.x;
    if (b < 64)      prep_body(W1, w1f, 252, 128, 8, b);
    else if (b < 80) prep_body(W2, w2f, 128, 64, 4, b - 64);
    else             prep_body(W3, w3f, 64, 5, 2, b - 80);
}

// ---------------------------------------------------------------------------
// K1: front MLP.  4 waves/block, each wave OWNS 16 rows (wave-local LDS, no
// __syncthreads).  Each block processes TILES_PER_BLOCK row-tiles of 64 rows,
// software-pipelined: the whole A-tile (16 fp32x4 regs/lane = 16KB/wave) for
// tile t+1 is issued right after tile t's a-fragments are extracted, hiding
// global-load latency under GEMM1/2/3 compute.
// ---------------------------------------------------------------------------
__global__ __launch_bounds__(256) void front_kernel(
    const float* __restrict__ state,
    const _Float16* __restrict__ w1f, const float* __restrict__ b1,
    const _Float16* __restrict__ w2f, const float* __restrict__ b2,
    const _Float16* __restrict__ w3f, const float* __restrict__ b3,
    float* __restrict__ enc) {
    __shared__ char lds[24576];      // h1: [64][256B] @0, h2: [64][128B] @16384
    const int tid = threadIdx.x;
    const int w   = tid >> 6;
    const int l   = tid & 63;
    const int l15 = l & 15;
    const int lhi = l >> 4;
    const int wrow = w * 16;                       // wave-local row offset
    const int tile0 = blockIdx.x * TILES_PER_BLOCK;

    floatx4 pf0[8], pf1[8];   // prefetch buffer: one full 16x256 A-subtile

#define ISSUE_A(TILE)                                                          \
    {                                                                          \
        const float* Ap = state + (size_t)((TILE) * 64 + wrow + l15) * 252;    \
        _Pragma("unroll")                                                      \
        for (int ks = 0; ks < 8; ++ks) {                                       \
            int c0 = ks * 32 + lhi * 8;                                        \
            pf0[ks] = *(const floatx4*)(Ap + c0);                              \
            if (c0 + 8 <= 252) pf1[ks] = *(const floatx4*)(Ap + c0 + 4);       \
            else               pf1[ks] = floatx4{0, 0, 0, 0};                  \
        }                                                                      \
    }

    ISSUE_A(tile0)

#pragma unroll
    for (int t = 0; t < TILES_PER_BLOCK; ++t) {
        const int tile = tile0 + t;

        // ---- extract all a-frags (consumes pf), then issue next tile's loads
        half8_t af[8];
#pragma unroll
        for (int ks = 0; ks < 8; ++ks) {
            floatx4 f0 = pf0[ks], f1 = pf1[ks];
            af[ks] = half8_t{ (_Float16)f0[0], (_Float16)f0[1], (_Float16)f0[2], (_Float16)f0[3],
                              (_Float16)f1[0], (_Float16)f1[1], (_Float16)f1[2], (_Float16)f1[3] };
        }
        if (t + 1 < TILES_PER_BLOCK) ISSUE_A(tile + 1)

        // ---- GEMM1: [16 x 256] @ [256 x 128] ----
        floatx4 acc1[8];
#pragma unroll
        for (int nt = 0; nt < 8; ++nt) acc1[nt] = floatx4{0, 0, 0, 0};
#pragma unroll
        for (int ks = 0; ks < 8; ++ks) {
#pragma unroll
            for (int nt = 0; nt < 8; ++nt) {
                half8_t bf = *(const half8_t*)(w1f + (size_t)((nt * 8 + ks) * 64 + l) * 8);
                acc1[nt] = __builtin_amdgcn_mfma_f32_16x16x32_f16(af[ks], bf, acc1[nt], 0, 0, 0);
            }
        }

        // ---- h1 = relu(acc1 + b1) -> LDS, wave-local rows, swizzled ----
#pragma unroll
        for (int nt = 0; nt < 8; ++nt) {
            int col = nt * 16 + l15;
            float bb = b1[col];
#pragma unroll
            for (int ri = 0; ri < 4; ++ri) {
                int r = wrow + lhi * 4 + ri;
                float v = acc1[nt][ri] + bb;
                v = v > 0.f ? v : 0.f;
                int byte = (r << 8) + ((col * 2) ^ ((r & 7) << 4));
                *(_Float16*)(lds + byte) = (_Float16)v;
            }
        }

        // ---- GEMM2: K = 128 (4 steps), N = 64 ----
        floatx4 acc2[4];
#pragma unroll
        for (int nt = 0; nt < 4; ++nt) acc2[nt] = floatx4{0, 0, 0, 0};
#pragma unroll
        for (int ks = 0; ks < 4; ++ks) {
            int r = wrow + l15;
            int byte = (r << 8) + (((ks * 64) + lhi * 16) ^ ((r & 7) << 4));
            half8_t a = *(const half8_t*)(lds + byte);
#pragma unroll
            for (int nt = 0; nt < 4; ++nt) {
                half8_t bf = *(const half8_t*)(w2f + (size_t)((nt * 4 + ks) * 64 + l) * 8);
                acc2[nt] = __builtin_amdgcn_mfma_f32_16x16x32_f16(a, bf, acc2[nt], 0, 0, 0);
            }
        }

        // ---- h2 = relu(acc2 + b2) -> LDS @16384, wave-local, swizzled ----
#pragma unroll
        for (int nt = 0; nt < 4; ++nt) {
            int col = nt * 16 + l15;
            float bb = b2[col];
#pragma unroll
            for (int ri = 0; ri < 4; ++ri) {
                int r = wrow + lhi * 4 + ri;
                float v = acc2[nt][ri] + bb;
                v = v > 0.f ? v : 0.f;
                int byte = 16384 + (r << 7) + ((col * 2) ^ ((r & 7) << 4));
                *(_Float16*)(lds + byte) = (_Float16)v;
            }
        }

        // ---- GEMM3: K = 64 (2 steps), N = 16 (cols 0..4 valid) ----
        floatx4 acc3 = floatx4{0, 0, 0, 0};
#pragma unroll
        for (int ks = 0; ks < 2; ++ks) {
            int r = wrow + l15;
            int byte = 16384 + (r << 7) + (((ks * 64) + lhi * 16) ^ ((r & 7) << 4));
            half8_t a = *(const half8_t*)(lds + byte);
            half8_t bf = *(const half8_t*)(w3f + (size_t)(ks * 64 + l) * 8);
            acc3 = __builtin_amdgcn_mfma_f32_16x16x32_f16(a, bf, acc3, 0, 0, 0);
        }

        // ---- enc = tanh(acc3 + b3), cols 0..4 ----
        if (l15 < 5) {
            float bb = b3[l15];
#pragma unroll
            for (int ri = 0; ri < 4; ++ri) {
                int r = tile * 64 + wrow + lhi * 4 + ri;
                enc[(size_t)r * 5 + l15] = tanhf(acc3[ri] + bb);
            }
        }
    }
#undef ISSUE_A
}

// ---------------------------------------------------------------------------
// K2: quantum circuit + back MLP, one thread per batch row.
// wire w <-> bit (4-w) of the flat amplitude index (wire 0 = MSB).
// ---------------------------------------------------------------------------
template<int P>
__device__ __forceinline__ void ry_g(float* re, float* im, float c, float s) {
    constexpr int STR = 1 << P;
#pragma unroll
    for (int base = 0; base < 32; base += 2 * STR)
#pragma unroll
        for (int d = 0; d < STR; ++d) {
            int i0 = base + d, i1 = i0 + STR;
            float r0 = re[i0], r1 = re[i1], m0 = im[i0], m1 = im[i1];
            re[i0] = c * r0 - s * r1;  re[i1] = s * r0 + c * r1;
            im[i0] = c * m0 - s * m1;  im[i1] = s * m0 + c * m1;
        }
}

template<int P>
__device__ __forceinline__ void rz_g(float* re, float* im, float c, float s) {
#pragma unroll
    for (int i = 0; i < 32; ++i) {
        float t = ((i >> P) & 1) ? s : -s;    // bit0: e^{-i h}, bit1: e^{+i h}
        float r = re[i], m = im[i];
        re[i] = c * r - t * m;
        im[i] = c * m + t * r;
    }
}

template<int PC, int PT>
__device__ __forceinline__ void cnot_g(float* re, float* im) {
#pragma unroll
    for (int i = 0; i < 32; ++i) {
        if (((i >> PC) & 1) && !((i >> PT) & 1)) {
            int j = i | (1 << PT);
            float t;
            t = re[i]; re[i] = re[j]; re[j] = t;
            t = im[i]; im[i] = im[j]; im[j] = t;
        }
    }
}

__global__ __launch_bounds__(256) void back_kernel(
    const float* __restrict__ enc, const float* __restrict__ qp,
    const float* __restrict__ D1, const float* __restrict__ d1,
    const float* __restrict__ D2, const float* __restrict__ d2,
    const float* __restrict__ D3, const float* __restrict__ d3,
    float* __restrict__ out) {
    __shared__ float sD1[160], sd1[32], sD2[512], sd2[16], sD3[64], sd3[4];
    __shared__ float sQc[30], sQs[30];
    const int tid = threadIdx.x;
    for (int i = tid; i < 512; i += 256) sD2[i] = D2[i];
    if (tid < 160) sD1[tid] = D1[tid];
    if (tid < 32)  sd1[tid] = d1[tid];
    if (tid < 64)  sD3[tid] = D3[tid];
    if (tid < 16)  sd2[tid] = d2[tid];
    if (tid < 4)   sd3[tid] = d3[tid];
    if (tid < 30) { float h = 0.5f * qp[tid]; sQc[tid] = cosf(h); sQs[tid] = sinf(h); }
    __syncthreads();

    const size_t r = (size_t)blockIdx.x * 256 + tid;

    // encoding: product state from RY(enc_i * pi) on |0...0>
    float cq[5], sq[5];
    const float HPI = 1.57079632679489662f;   // pi/2
#pragma unroll
    for (int i = 0; i < 5; ++i) {
        float a = enc[r * 5 + i] * HPI;
        cq[i] = cosf(a);
        sq[i] = sinf(a);
    }
    float re[32], im[32];
#pragma unroll
    for (int i = 0; i < 32; ++i) {
        float v = ((i >> 4) & 1) ? sq[0] : cq[0];
        v *= ((i >> 3) & 1) ? sq[1] : cq[1];
        v *= ((i >> 2) & 1) ? sq[2] : cq[2];
        v *= ((i >> 1) & 1) ? sq[3] : cq[3];
        v *= ( i       & 1) ? sq[4] : cq[4];
        re[i] = v;
        im[i] = 0.f;
    }

#pragma unroll
    for (int lay = 0; lay < 3; ++lay) {
        const float* c = sQc + lay * 10;
        const float* s = sQs + lay * 10;
        ry_g<4>(re, im, c[0], s[0]);  rz_g<4>(re, im, c[1], s[1]);
        ry_g<3>(re, im, c[2], s[2]);  rz_g<3>(re, im, c[3], s[3]);
        ry_g<2>(re, im, c[4], s[4]);  rz_g<2>(re, im, c[5], s[5]);
        ry_g<1>(re, im, c[6], s[6]);  rz_g<1>(re, im, c[7], s[7]);
        ry_g<0>(re, im, c[8], s[8]);  rz_g<0>(re, im, c[9], s[9]);
        cnot_g<4, 3>(re, im);
        cnot_g<3, 2>(re, im);
        cnot_g<2, 1>(re, im);
        cnot_g<1, 0>(re, im);
    }

    float q[5] = {0, 0, 0, 0, 0};
#pragma unroll
    for (int i = 0; i < 32; ++i) {
        float p = re[i] * re[i] + im[i] * im[i];
        q[0] += ((i >> 4) & 1) ? -p : p;
        q[1] += ((i >> 3) & 1) ? -p : p;
        q[2] += ((i >> 2) & 1) ? -p : p;
        q[3] += ((i >> 1) & 1) ? -p : p;
        q[4] += ( i       & 1) ? -p : p;
    }

    // back MLP: q(5) -> 32 relu -> 16 relu -> 4
    float h1[32];
#pragma unroll
    for (int j = 0; j < 32; ++j) {
        float a = sd1[j];
#pragma unroll
        for (int k = 0; k < 5; ++k) a += q[k] * sD1[k * 32 + j];
        h1[j] = a > 0.f ? a : 0.f;
    }
    float h2[16];
#pragma unroll
    for (int j = 0; j < 16; ++j) {
        float a = sd2[j];
#pragma unroll
        for (int k = 0; k < 32; ++k) a += h1[k] * sD2[k * 16 + j];
        h2[j] = a > 0.f ? a : 0.f;
    }
    floatx4 o;
#pragma unroll
    for (int j = 0; j < 4; ++j) {
        float a = sd3[j];
#pragma unroll
        for (int k = 0; k < 16; ++k) a += h2[k] * sD3[k * 4 + j];
        o[j] = a;
    }
    *(floatx4*)(out + r * 4) = o;
}

// ---------------------------------------------------------------------------
extern "C" void kernel_launch(void* const* d_in, const int* in_sizes, int n_in,
                              void* d_out, int out_size, void* d_ws, size_t ws_size,
                              hipStream_t stream) {
    const float* state = (const float*)d_in[0];
    const float* W1 = (const float*)d_in[1];
    const float* b1 = (const float*)d_in[2];
    const float* W2 = (const float*)d_in[3];
    const float* b2 = (const float*)d_in[4];
    const float* W3 = (const float*)d_in[5];
    const float* b3 = (const float*)d_in[6];
    const float* qp = (const float*)d_in[7];
    const float* D1 = (const float*)d_in[8];
    const float* d1 = (const float*)d_in[9];
    const float* D2 = (const float*)d_in[10];
    const float* d2 = (const float*)d_in[11];
    const float* D3 = (const float*)d_in[12];
    const float* d3 = (const float*)d_in[13];
    float* out = (float*)d_out;

    const int B = in_sizes[0] / 252;     // 131072

    char* ws = (char*)d_ws;
    _Float16* w1f = (_Float16*)ws;                         // 64 frag-blocks = 64 KB
    _Float16* w2f = (_Float16*)(ws + 65536);               // 16 -> 16 KB
    _Float16* w3f = (_Float16*)(ws + 65536 + 16384);       // 2  -> 2 KB
    float*    enc = (float*)(ws + 65536 + 16384 + 2048);   // B*5 fp32

    prep_all<<<82, 64, 0, stream>>>(W1, W2, W3, w1f, w2f, w3f);
    front_kernel<<<B / (64 * TILES_PER_BLOCK), 256, 0, stream>>>(
        state, w1f, b1, w2f, b2, w3f, b3, enc);
    back_kernel<<<B / 256, 256, 0, stream>>>(enc, qp, D1, d1, D2, d2, D3, d3, out);
}

// Round 4
// 65.060 us; speedup vs baseline: 1.6383x; 1.6383x over previous
//
#include <hip/hip_runtime.h>
#include <hip/hip_bf16.h>
#include <math.h>

typedef _Float16 half8_t __attribute__((ext_vector_type(8)));
typedef _Float16 half4_t __attribute__((ext_vector_type(4)));
typedef float floatx4 __attribute__((ext_vector_type(4)));

// ---------------------------------------------------------------------------
// K0: repack fp32 weights (K x N row-major) into fp16 MFMA B-fragment layout:
// dst[((nt*KS+ks)*64 + lane)*8 + j] = (half) W[ks*32 + (lane>>4)*8 + j][nt*16 + (lane&15)]
// zero-padded for k >= K or col >= N.  One merged launch for W1/W2/W3.
// ---------------------------------------------------------------------------
__device__ __forceinline__ void prep_body(const float* __restrict__ W,
                                          _Float16* __restrict__ dst,
                                          int K, int N, int KS, int b) {
    int ks   = b % KS;
    int nt   = b / KS;
    int lane = threadIdx.x;         // 64
    int col  = nt * 16 + (lane & 15);
    int kbase = ks * 32 + ((lane >> 4) << 3);
    half8_t v;
#pragma unroll
    for (int j = 0; j < 8; ++j) {
        int k = kbase + j;
        float x = (k < K && col < N) ? W[(size_t)k * N + col] : 0.f;
        v[j] = (_Float16)x;
    }
    *(half8_t*)(dst + (size_t)(b * 64 + lane) * 8) = v;
}

__global__ void prep_all(const float* __restrict__ W1, const float* __restrict__ W2,
                         const float* __restrict__ W3,
                         _Float16* __restrict__ w1f, _Float16* __restrict__ w2f,
                         _Float16* __restrict__ w3f) {
    int b = blockIdx.x;
    if (b < 64)      prep_body(W1, w1f, 252, 128, 8, b);
    else if (b < 80) prep_body(W2, w2f, 128, 64, 4, b - 64);
    else             prep_body(W3, w3f, 64, 5, 2, b - 80);
}

// ---------------------------------------------------------------------------
// K1: front MLP, N-split across waves, B-fragments register-resident.
//   - 64 rows/block, 256 threads (4 waves), grid = B/64 = 2048.
//   - Each wave holds its column-slice of W1/W2/W3 frags in VGPRs (22 frags,
//     88 VGPR) -> ZERO weight loads in the compute path.
//   - A staged cooperatively: wave w converts rows w*16..+15 fp32->fp16 into
//     swizzled LDS (coalesced 1KB global loads), all waves read a-frags.
//   - LDS 32KB total: sA [64][256]f16 @0 (reused for h1 [64][128]f16 after
//     barrier), h2 [64][64]f16 @16384.
//   - GEMM1: wave w -> h1 cols w*32..+32 (all 64 rows).
//     GEMM2: wave w -> h2 cols w*16..+16.  GEMM3: wave w -> rows w*16..+16.
// ---------------------------------------------------------------------------
__global__ __launch_bounds__(256, 3) void front_kernel(
    const float* __restrict__ state,
    const _Float16* __restrict__ w1f, const float* __restrict__ b1,
    const _Float16* __restrict__ w2f, const float* __restrict__ b2,
    const _Float16* __restrict__ w3f, const float* __restrict__ b3,
    float* __restrict__ enc) {
    __shared__ char lds[32768];
    const int tid = threadIdx.x;
    const int w   = tid >> 6;
    const int l   = tid & 63;
    const int l15 = l & 15;
    const int lhi = l >> 4;
    const int wrow = w * 16;
    const int rowbase = blockIdx.x * 64;

    // ---- B-fragment preload (L2-resident after block 0), held in VGPRs ----
    half8_t bw1[2][8], bw2[4], bw3[2];
#pragma unroll
    for (int ntl = 0; ntl < 2; ++ntl)
#pragma unroll
        for (int ks = 0; ks < 8; ++ks)
            bw1[ntl][ks] = *(const half8_t*)(w1f + (size_t)(((w * 2 + ntl) * 8 + ks) * 64 + l) * 8);
#pragma unroll
    for (int ks = 0; ks < 4; ++ks)
        bw2[ks] = *(const half8_t*)(w2f + (size_t)((w * 4 + ks) * 64 + l) * 8);
#pragma unroll
    for (int ks = 0; ks < 2; ++ks)
        bw3[ks] = *(const half8_t*)(w3f + (size_t)(ks * 64 + l) * 8);

    // ---- stage A: wave w stages its 16 rows, coalesced 64B/row segments ----
    // lane -> (row = l>>2, chunk = l&3); instr i covers float cols i*16+chunk*4.
    {
        const int srow = wrow + (l >> 2);
        const int sc   = (l & 3) * 4;
        const float* Arow = state + (size_t)(rowbase + srow) * 252;
        const int swz = (srow & 7) << 4;
#pragma unroll
        for (int i = 0; i < 16; ++i) {
            int cf = i * 16 + sc;            // first float col of this 16B chunk
            half4_t h;
            if (cf < 252) {                  // (i==15 && chunk==3) is the K-pad
                floatx4 f = *(const floatx4*)(Arow + cf);
                h = half4_t{ (_Float16)f[0], (_Float16)f[1], (_Float16)f[2], (_Float16)f[3] };
            } else {
                h = half4_t{ 0, 0, 0, 0 };
            }
            int cb = cf * 2;                 // fp16 byte col, 0..504
            *(half4_t*)(lds + (srow << 9) + (cb ^ swz)) = h;
        }
    }
    __syncthreads();

    // ---- GEMM1: [64 x 256] @ [256 x 32(cols w*32..)] ----
    floatx4 acc1[4][2];
#pragma unroll
    for (int mi = 0; mi < 4; ++mi)
#pragma unroll
        for (int ntl = 0; ntl < 2; ++ntl) acc1[mi][ntl] = floatx4{0, 0, 0, 0};

#pragma unroll
    for (int ks = 0; ks < 8; ++ks) {
        half8_t a[4];
#pragma unroll
        for (int mi = 0; mi < 4; ++mi) {
            int r = mi * 16 + l15;
            int cb = ks * 64 + lhi * 16;
            a[mi] = *(const half8_t*)(lds + (r << 9) + (cb ^ ((r & 7) << 4)));
        }
#pragma unroll
        for (int mi = 0; mi < 4; ++mi) {
#pragma unroll
            for (int ntl = 0; ntl < 2; ++ntl)
                acc1[mi][ntl] = __builtin_amdgcn_mfma_f32_16x16x32_f16(a[mi], bw1[ntl][ks], acc1[mi][ntl], 0, 0, 0);
        }
    }
    __syncthreads();   // all waves done reading sA before h1 overwrites it

    // ---- h1 = relu(acc1 + b1) -> LDS [64][128]f16 @0, swizzled ----
#pragma unroll
    for (int ntl = 0; ntl < 2; ++ntl) {
        int col = (w * 2 + ntl) * 16 + l15;
        float bb = b1[col];
#pragma unroll
        for (int mi = 0; mi < 4; ++mi) {
#pragma unroll
            for (int ri = 0; ri < 4; ++ri) {
                int row = mi * 16 + lhi * 4 + ri;
                float v = acc1[mi][ntl][ri] + bb;
                v = v > 0.f ? v : 0.f;
                *(_Float16*)(lds + (row << 8) + ((col * 2) ^ ((row & 7) << 4))) = (_Float16)v;
            }
        }
    }
    __syncthreads();

    // ---- GEMM2: [64 x 128] @ [128 x 16(cols w*16..)] ----
    floatx4 acc2[4];
#pragma unroll
    for (int mi = 0; mi < 4; ++mi) acc2[mi] = floatx4{0, 0, 0, 0};
#pragma unroll
    for (int ks = 0; ks < 4; ++ks) {
#pragma unroll
        for (int mi = 0; mi < 4; ++mi) {
            int r = mi * 16 + l15;
            int cb = ks * 64 + lhi * 16;
            half8_t a = *(const half8_t*)(lds + (r << 8) + (cb ^ ((r & 7) << 4)));
            acc2[mi] = __builtin_amdgcn_mfma_f32_16x16x32_f16(a, bw2[ks], acc2[mi], 0, 0, 0);
        }
    }

    // ---- h2 = relu(acc2 + b2) -> LDS [64][64]f16 @16384 (disjoint region) ----
    {
        int col = w * 16 + l15;
        float bb = b2[col];
#pragma unroll
        for (int mi = 0; mi < 4; ++mi) {
#pragma unroll
            for (int ri = 0; ri < 4; ++ri) {
                int row = mi * 16 + lhi * 4 + ri;
                float v = acc2[mi][ri] + bb;
                v = v > 0.f ? v : 0.f;
                *(_Float16*)(lds + 16384 + (row << 7) + ((col * 2) ^ ((row & 7) << 4))) = (_Float16)v;
            }
        }
    }
    __syncthreads();

    // ---- GEMM3: rows w*16..+15, [16 x 64] @ [64 x 16] (cols 0..4 valid) ----
    floatx4 acc3 = floatx4{0, 0, 0, 0};
#pragma unroll
    for (int ks = 0; ks < 2; ++ks) {
        int r = wrow + l15;
        int cb = ks * 64 + lhi * 16;
        half8_t a = *(const half8_t*)(lds + 16384 + (r << 7) + (cb ^ ((r & 7) << 4)));
        acc3 = __builtin_amdgcn_mfma_f32_16x16x32_f16(a, bw3[ks], acc3, 0, 0, 0);
    }

    // ---- enc = tanh(acc3 + b3), cols 0..4 ----
    if (l15 < 5) {
        float bb = b3[l15];
#pragma unroll
        for (int ri = 0; ri < 4; ++ri) {
            int row = rowbase + wrow + lhi * 4 + ri;
            enc[(size_t)row * 5 + l15] = tanhf(acc3[ri] + bb);
        }
    }
}

// ---------------------------------------------------------------------------
// K2: quantum circuit + back MLP, one thread per batch row.
// wire w <-> bit (4-w) of the flat amplitude index (wire 0 = MSB).
// ---------------------------------------------------------------------------
template<int P>
__device__ __forceinline__ void ry_g(float* re, float* im, float c, float s) {
    constexpr int STR = 1 << P;
#pragma unroll
    for (int base = 0; base < 32; base += 2 * STR)
#pragma unroll
        for (int d = 0; d < STR; ++d) {
            int i0 = base + d, i1 = i0 + STR;
            float r0 = re[i0], r1 = re[i1], m0 = im[i0], m1 = im[i1];
            re[i0] = c * r0 - s * r1;  re[i1] = s * r0 + c * r1;
            im[i0] = c * m0 - s * m1;  im[i1] = s * m0 + c * m1;
        }
}

template<int P>
__device__ __forceinline__ void rz_g(float* re, float* im, float c, float s) {
#pragma unroll
    for (int i = 0; i < 32; ++i) {
        float t = ((i >> P) & 1) ? s : -s;    // bit0: e^{-i h}, bit1: e^{+i h}
        float r = re[i], m = im[i];
        re[i] = c * r - t * m;
        im[i] = c * m + t * r;
    }
}

template<int PC, int PT>
__device__ __forceinline__ void cnot_g(float* re, float* im) {
#pragma unroll
    for (int i = 0; i < 32; ++i) {
        if (((i >> PC) & 1) && !((i >> PT) & 1)) {
            int j = i | (1 << PT);
            float t;
            t = re[i]; re[i] = re[j]; re[j] = t;
            t = im[i]; im[i] = im[j]; im[j] = t;
        }
    }
}

__global__ __launch_bounds__(256) void back_kernel(
    const float* __restrict__ enc, const float* __restrict__ qp,
    const float* __restrict__ D1, const float* __restrict__ d1,
    const float* __restrict__ D2, const float* __restrict__ d2,
    const float* __restrict__ D3, const float* __restrict__ d3,
    float* __restrict__ out) {
    __shared__ float sD1[160], sd1[32], sD2[512], sd2[16], sD3[64], sd3[4];
    __shared__ float sQc[30], sQs[30];
    const int tid = threadIdx.x;
    for (int i = tid; i < 512; i += 256) sD2[i] = D2[i];
    if (tid < 160) sD1[tid] = D1[tid];
    if (tid < 32)  sd1[tid] = d1[tid];
    if (tid < 64)  sD3[tid] = D3[tid];
    if (tid < 16)  sd2[tid] = d2[tid];
    if (tid < 4)   sd3[tid] = d3[tid];
    if (tid < 30) { float h = 0.5f * qp[tid]; sQc[tid] = cosf(h); sQs[tid] = sinf(h); }
    __syncthreads();

    const size_t r = (size_t)blockIdx.x * 256 + tid;

    // encoding: product state from RY(enc_i * pi) on |0...0>
    float cq[5], sq[5];
    const float HPI = 1.57079632679489662f;   // pi/2
#pragma unroll
    for (int i = 0; i < 5; ++i) {
        float a = enc[r * 5 + i] * HPI;
        cq[i] = cosf(a);
        sq[i] = sinf(a);
    }
    float re[32], im[32];
#pragma unroll
    for (int i = 0; i < 32; ++i) {
        float v = ((i >> 4) & 1) ? sq[0] : cq[0];
        v *= ((i >> 3) & 1) ? sq[1] : cq[1];
        v *= ((i >> 2) & 1) ? sq[2] : cq[2];
        v *= ((i >> 1) & 1) ? sq[3] : cq[3];
        v *= ( i       & 1) ? sq[4] : cq[4];
        re[i] = v;
        im[i] = 0.f;
    }

#pragma unroll
    for (int lay = 0; lay < 3; ++lay) {
        const float* c = sQc + lay * 10;
        const float* s = sQs + lay * 10;
        ry_g<4>(re, im, c[0], s[0]);  rz_g<4>(re, im, c[1], s[1]);
        ry_g<3>(re, im, c[2], s[2]);  rz_g<3>(re, im, c[3], s[3]);
        ry_g<2>(re, im, c[4], s[4]);  rz_g<2>(re, im, c[5], s[5]);
        ry_g<1>(re, im, c[6], s[6]);  rz_g<1>(re, im, c[7], s[7]);
        ry_g<0>(re, im, c[8], s[8]);  rz_g<0>(re, im, c[9], s[9]);
        cnot_g<4, 3>(re, im);
        cnot_g<3, 2>(re, im);
        cnot_g<2, 1>(re, im);
        cnot_g<1, 0>(re, im);
    }

    float q[5] = {0, 0, 0, 0, 0};
#pragma unroll
    for (int i = 0; i < 32; ++i) {
        float p = re[i] * re[i] + im[i] * im[i];
        q[0] += ((i >> 4) & 1) ? -p : p;
        q[1] += ((i >> 3) & 1) ? -p : p;
        q[2] += ((i >> 2) & 1) ? -p : p;
        q[3] += ((i >> 1) & 1) ? -p : p;
        q[4] += ( i       & 1) ? -p : p;
    }

    // back MLP: q(5) -> 32 relu -> 16 relu -> 4
    float h1[32];
#pragma unroll
    for (int j = 0; j < 32; ++j) {
        float a = sd1[j];
#pragma unroll
        for (int k = 0; k < 5; ++k) a += q[k] * sD1[k * 32 + j];
        h1[j] = a > 0.f ? a : 0.f;
    }
    float h2[16];
#pragma unroll
    for (int j = 0; j < 16; ++j) {
        float a = sd2[j];
#pragma unroll
        for (int k = 0; k < 32; ++k) a += h1[k] * sD2[k * 16 + j];
        h2[j] = a > 0.f ? a : 0.f;
    }
    floatx4 o;
#pragma unroll
    for (int j = 0; j < 4; ++j) {
        float a = sd3[j];
#pragma unroll
        for (int k = 0; k < 16; ++k) a += h2[k] * sD3[k * 4 + j];
        o[j] = a;
    }
    *(floatx4*)(out + r * 4) = o;
}

// ---------------------------------------------------------------------------
extern "C" void kernel_launch(void* const* d_in, const int* in_sizes, int n_in,
                              void* d_out, int out_size, void* d_ws, size_t ws_size,
                              hipStream_t stream) {
    const float* state = (const float*)d_in[0];
    const float* W1 = (const float*)d_in[1];
    const float* b1 = (const float*)d_in[2];
    const float* W2 = (const float*)d_in[3];
    const float* b2 = (const float*)d_in[4];
    const float* W3 = (const float*)d_in[5];
    const float* b3 = (const float*)d_in[6];
    const float* qp = (const float*)d_in[7];
    const float* D1 = (const float*)d_in[8];
    const float* d1 = (const float*)d_in[9];
    const float* D2 = (const float*)d_in[10];
    const float* d2 = (const float*)d_in[11];
    const float* D3 = (const float*)d_in[12];
    const float* d3 = (const float*)d_in[13];
    float* out = (float*)d_out;

    const int B = in_sizes[0] / 252;     // 131072

    char* ws = (char*)d_ws;
    _Float16* w1f = (_Float16*)ws;                         // 64 frag-blocks = 64 KB
    _Float16* w2f = (_Float16*)(ws + 65536);               // 16 -> 16 KB
    _Float16* w3f = (_Float16*)(ws + 65536 + 16384);       // 2  -> 2 KB
    float*    enc = (float*)(ws + 65536 + 16384 + 2048);   // B*5 fp32

    prep_all<<<82, 64, 0, stream>>>(W1, W2, W3, w1f, w2f, w3f);
    front_kernel<<<B / 64, 256, 0, stream>>>(state, w1f, b1, w2f, b2, w3f, b3, enc);
    back_kernel<<<B / 256, 256, 0, stream>>>(enc, qp, D1, d1, D2, d2, D3, d3, out);
}

// Round 5
// 61.679 us; speedup vs baseline: 1.7281x; 1.0548x over previous
//
#include <hip/hip_runtime.h>
#include <hip/hip_bf16.h>
#include <math.h>

typedef _Float16 half8_t __attribute__((ext_vector_type(8)));
typedef _Float16 half4_t __attribute__((ext_vector_type(4)));
typedef float floatx4 __attribute__((ext_vector_type(4)));

// ---------------------------------------------------------------------------
// K0: repack fp32 weights (K x N row-major) into fp16 MFMA B-fragment layout:
// dst[((nt*KS+ks)*64 + lane)*8 + j] = (half) W[ks*32 + (lane>>4)*8 + j][nt*16 + (lane&15)]
// zero-padded for k >= K or col >= N.  One merged launch for W1/W2/W3.
// ---------------------------------------------------------------------------
__device__ __forceinline__ void prep_body(const float* __restrict__ W,
                                          _Float16* __restrict__ dst,
                                          int K, int N, int KS, int b) {
    int ks   = b % KS;
    int nt   = b / KS;
    int lane = threadIdx.x;         // 64
    int col  = nt * 16 + (lane & 15);
    int kbase = ks * 32 + ((lane >> 4) << 3);
    half8_t v;
#pragma unroll
    for (int j = 0; j < 8; ++j) {
        int k = kbase + j;
        float x = (k < K && col < N) ? W[(size_t)k * N + col] : 0.f;
        v[j] = (_Float16)x;
    }
    *(half8_t*)(dst + (size_t)(b * 64 + lane) * 8) = v;
}

__global__ void prep_all(const float* __restrict__ W1, const float* __restrict__ W2,
                         const float* __restrict__ W3,
                         _Float16* __restrict__ w1f, _Float16* __restrict__ w2f,
                         _Float16* __restrict__ w3f) {
    int b = blockIdx.x;
    if (b < 64)      prep_body(W1, w1f, 252, 128, 8, b);
    else if (b < 80) prep_body(W2, w2f, 128, 64, 4, b - 64);
    else             prep_body(W3, w3f, 64, 5, 2, b - 80);
}

// ---------------------------------------------------------------------------
// K1: front MLP, N-split across waves, B-fragments register-resident.
//   - 64 rows/block, 256 threads (4 waves), grid = B/64 = 2048.
//   - ORDER MATTERS for VGPR pressure: A-stage (16 fp32x4 in flight = 64
//     VGPR) runs FIRST; the 22 B-fragments (88 VGPR, live to the end) are
//     loaded after, overlapped with the A-load drain at the barrier.
//   - LDS 32KB: sA [64][256]f16 @0 (reused for h1 after barrier),
//     h2 [64][64]f16 @16384.  All tiles XOR-swizzled (byte ^= (row&7)<<4).
//   - GEMM1: wave w -> h1 cols w*32..+32.  GEMM2: wave w -> h2 cols w*16..
//     GEMM3: wave w -> rows w*16..+16 -> tanh -> enc.
// ---------------------------------------------------------------------------
__global__ __launch_bounds__(256, 3) void front_kernel(
    const float* __restrict__ state,
    const _Float16* __restrict__ w1f, const float* __restrict__ b1,
    const _Float16* __restrict__ w2f, const float* __restrict__ b2,
    const _Float16* __restrict__ w3f, const float* __restrict__ b3,
    float* __restrict__ enc) {
    __shared__ char lds[32768];
    const int tid = threadIdx.x;
    const int w   = tid >> 6;
    const int l   = tid & 63;
    const int l15 = l & 15;
    const int lhi = l >> 4;
    const int wrow = w * 16;
    const int rowbase = blockIdx.x * 64;

    // ---- stage A FIRST: wave w stages its 16 rows (coalesced 64B/row/instr)
    // lane -> (row = l>>2, chunk = l&3); instr i covers float cols i*16+chunk*4.
    {
        const int srow = wrow + (l >> 2);
        const int sc   = (l & 3) * 4;
        const float* Arow = state + (size_t)(rowbase + srow) * 252;
        const int swz = (srow & 7) << 4;
#pragma unroll
        for (int i = 0; i < 16; ++i) {
            int cf = i * 16 + sc;            // first float col of this 16B chunk
            half4_t h;
            if (cf < 252) {                  // (i==15 && chunk==3) is the K-pad
                floatx4 f = *(const floatx4*)(Arow + cf);
                h = half4_t{ (_Float16)f[0], (_Float16)f[1], (_Float16)f[2], (_Float16)f[3] };
            } else {
                h = half4_t{ 0, 0, 0, 0 };
            }
            int cb = cf * 2;                 // fp16 byte col, 0..504
            *(half4_t*)(lds + (srow << 9) + (cb ^ swz)) = h;
        }
    }

    // ---- B-fragment preload (L2-resident), issued while A-loads drain ----
    half8_t bw1[2][8], bw2[4], bw3[2];
#pragma unroll
    for (int ntl = 0; ntl < 2; ++ntl)
#pragma unroll
        for (int ks = 0; ks < 8; ++ks)
            bw1[ntl][ks] = *(const half8_t*)(w1f + (size_t)(((w * 2 + ntl) * 8 + ks) * 64 + l) * 8);
#pragma unroll
    for (int ks = 0; ks < 4; ++ks)
        bw2[ks] = *(const half8_t*)(w2f + (size_t)((w * 4 + ks) * 64 + l) * 8);
#pragma unroll
    for (int ks = 0; ks < 2; ++ks)
        bw3[ks] = *(const half8_t*)(w3f + (size_t)(ks * 64 + l) * 8);

    __syncthreads();

    // ---- GEMM1: [64 x 256] @ [256 x 32(cols w*32..)] ----
    floatx4 acc1[4][2];
#pragma unroll
    for (int mi = 0; mi < 4; ++mi)
#pragma unroll
        for (int ntl = 0; ntl < 2; ++ntl) acc1[mi][ntl] = floatx4{0, 0, 0, 0};

#pragma unroll
    for (int ks = 0; ks < 8; ++ks) {
        half8_t a[4];
#pragma unroll
        for (int mi = 0; mi < 4; ++mi) {
            int r = mi * 16 + l15;
            int cb = ks * 64 + lhi * 16;
            a[mi] = *(const half8_t*)(lds + (r << 9) + (cb ^ ((r & 7) << 4)));
        }
#pragma unroll
        for (int mi = 0; mi < 4; ++mi) {
#pragma unroll
            for (int ntl = 0; ntl < 2; ++ntl)
                acc1[mi][ntl] = __builtin_amdgcn_mfma_f32_16x16x32_f16(a[mi], bw1[ntl][ks], acc1[mi][ntl], 0, 0, 0);
        }
    }
    __syncthreads();   // all waves done reading sA before h1 overwrites it

    // ---- h1 = relu(acc1 + b1) -> LDS [64][128]f16 @0, swizzled ----
#pragma unroll
    for (int ntl = 0; ntl < 2; ++ntl) {
        int col = (w * 2 + ntl) * 16 + l15;
        float bb = b1[col];
#pragma unroll
        for (int mi = 0; mi < 4; ++mi) {
#pragma unroll
            for (int ri = 0; ri < 4; ++ri) {
                int row = mi * 16 + lhi * 4 + ri;
                float v = acc1[mi][ntl][ri] + bb;
                v = v > 0.f ? v : 0.f;
                *(_Float16*)(lds + (row << 8) + ((col * 2) ^ ((row & 7) << 4))) = (_Float16)v;
            }
        }
    }
    __syncthreads();

    // ---- GEMM2: [64 x 128] @ [128 x 16(cols w*16..)] ----
    floatx4 acc2[4];
#pragma unroll
    for (int mi = 0; mi < 4; ++mi) acc2[mi] = floatx4{0, 0, 0, 0};
#pragma unroll
    for (int ks = 0; ks < 4; ++ks) {
#pragma unroll
        for (int mi = 0; mi < 4; ++mi) {
            int r = mi * 16 + l15;
            int cb = ks * 64 + lhi * 16;
            half8_t a = *(const half8_t*)(lds + (r << 8) + (cb ^ ((r & 7) << 4)));
            acc2[mi] = __builtin_amdgcn_mfma_f32_16x16x32_f16(a, bw2[ks], acc2[mi], 0, 0, 0);
        }
    }

    // ---- h2 = relu(acc2 + b2) -> LDS [64][64]f16 @16384 (disjoint region) ----
    {
        int col = w * 16 + l15;
        float bb = b2[col];
#pragma unroll
        for (int mi = 0; mi < 4; ++mi) {
#pragma unroll
            for (int ri = 0; ri < 4; ++ri) {
                int row = mi * 16 + lhi * 4 + ri;
                float v = acc2[mi][ri] + bb;
                v = v > 0.f ? v : 0.f;
                *(_Float16*)(lds + 16384 + (row << 7) + ((col * 2) ^ ((row & 7) << 4))) = (_Float16)v;
            }
        }
    }
    __syncthreads();

    // ---- GEMM3: rows w*16..+15, [16 x 64] @ [64 x 16] (cols 0..4 valid) ----
    floatx4 acc3 = floatx4{0, 0, 0, 0};
#pragma unroll
    for (int ks = 0; ks < 2; ++ks) {
        int r = wrow + l15;
        int cb = ks * 64 + lhi * 16;
        half8_t a = *(const half8_t*)(lds + 16384 + (r << 7) + (cb ^ ((r & 7) << 4)));
        acc3 = __builtin_amdgcn_mfma_f32_16x16x32_f16(a, bw3[ks], acc3, 0, 0, 0);
    }

    // ---- enc = tanh(acc3 + b3), cols 0..4 ----
    if (l15 < 5) {
        float bb = b3[l15];
#pragma unroll
        for (int ri = 0; ri < 4; ++ri) {
            int row = rowbase + wrow + lhi * 4 + ri;
            enc[(size_t)row * 5 + l15] = tanhf(acc3[ri] + bb);
        }
    }
}

// ---------------------------------------------------------------------------
// K2: quantum circuit + back MLP, one thread per batch row.
// wire w <-> bit (4-w) of the flat amplitude index (wire 0 = MSB).
// ---------------------------------------------------------------------------
template<int P>
__device__ __forceinline__ void ry_g(float* re, float* im, float c, float s) {
    constexpr int STR = 1 << P;
#pragma unroll
    for (int base = 0; base < 32; base += 2 * STR)
#pragma unroll
        for (int d = 0; d < STR; ++d) {
            int i0 = base + d, i1 = i0 + STR;
            float r0 = re[i0], r1 = re[i1], m0 = im[i0], m1 = im[i1];
            re[i0] = c * r0 - s * r1;  re[i1] = s * r0 + c * r1;
            im[i0] = c * m0 - s * m1;  im[i1] = s * m0 + c * m1;
        }
}

template<int P>
__device__ __forceinline__ void rz_g(float* re, float* im, float c, float s) {
#pragma unroll
    for (int i = 0; i < 32; ++i) {
        float t = ((i >> P) & 1) ? s : -s;    // bit0: e^{-i h}, bit1: e^{+i h}
        float r = re[i], m = im[i];
        re[i] = c * r - t * m;
        im[i] = c * m + t * r;
    }
}

template<int PC, int PT>
__device__ __forceinline__ void cnot_g(float* re, float* im) {
#pragma unroll
    for (int i = 0; i < 32; ++i) {
        if (((i >> PC) & 1) && !((i >> PT) & 1)) {
            int j = i | (1 << PT);
            float t;
            t = re[i]; re[i] = re[j]; re[j] = t;
            t = im[i]; im[i] = im[j]; im[j] = t;
        }
    }
}

__global__ __launch_bounds__(256) void back_kernel(
    const float* __restrict__ enc, const float* __restrict__ qp,
    const float* __restrict__ D1, const float* __restrict__ d1,
    const float* __restrict__ D2, const float* __restrict__ d2,
    const float* __restrict__ D3, const float* __restrict__ d3,
    float* __restrict__ out) {
    __shared__ float sD1[160], sd1[32], sD2[512], sd2[16], sD3[64], sd3[4];
    __shared__ float sQc[30], sQs[30];
    const int tid = threadIdx.x;
    for (int i = tid; i < 512; i += 256) sD2[i] = D2[i];
    if (tid < 160) sD1[tid] = D1[tid];
    if (tid < 32)  sd1[tid] = d1[tid];
    if (tid < 64)  sD3[tid] = D3[tid];
    if (tid < 16)  sd2[tid] = d2[tid];
    if (tid < 4)   sd3[tid] = d3[tid];
    if (tid < 30) { float h = 0.5f * qp[tid]; sQc[tid] = cosf(h); sQs[tid] = sinf(h); }
    __syncthreads();

    const size_t r = (size_t)blockIdx.x * 256 + tid;

    // encoding: product state from RY(enc_i * pi) on |0...0>
    float cq[5], sq[5];
    const float HPI = 1.57079632679489662f;   // pi/2
#pragma unroll
    for (int i = 0; i < 5; ++i) {
        float a = enc[r * 5 + i] * HPI;
        cq[i] = cosf(a);
        sq[i] = sinf(a);
    }
    float re[32], im[32];
#pragma unroll
    for (int i = 0; i < 32; ++i) {
        float v = ((i >> 4) & 1) ? sq[0] : cq[0];
        v *= ((i >> 3) & 1) ? sq[1] : cq[1];
        v *= ((i >> 2) & 1) ? sq[2] : cq[2];
        v *= ((i >> 1) & 1) ? sq[3] : cq[3];
        v *= ( i       & 1) ? sq[4] : cq[4];
        re[i] = v;
        im[i] = 0.f;
    }

#pragma unroll
    for (int lay = 0; lay < 3; ++lay) {
        const float* c = sQc + lay * 10;
        const float* s = sQs + lay * 10;
        ry_g<4>(re, im, c[0], s[0]);  rz_g<4>(re, im, c[1], s[1]);
        ry_g<3>(re, im, c[2], s[2]);  rz_g<3>(re, im, c[3], s[3]);
        ry_g<2>(re, im, c[4], s[4]);  rz_g<2>(re, im, c[5], s[5]);
        ry_g<1>(re, im, c[6], s[6]);  rz_g<1>(re, im, c[7], s[7]);
        ry_g<0>(re, im, c[8], s[8]);  rz_g<0>(re, im, c[9], s[9]);
        cnot_g<4, 3>(re, im);
        cnot_g<3, 2>(re, im);
        cnot_g<2, 1>(re, im);
        cnot_g<1, 0>(re, im);
    }

    float q[5] = {0, 0, 0, 0, 0};
#pragma unroll
    for (int i = 0; i < 32; ++i) {
        float p = re[i] * re[i] + im[i] * im[i];
        q[0] += ((i >> 4) & 1) ? -p : p;
        q[1] += ((i >> 3) & 1) ? -p : p;
        q[2] += ((i >> 2) & 1) ? -p : p;
        q[3] += ((i >> 1) & 1) ? -p : p;
        q[4] += ( i       & 1) ? -p : p;
    }

    // back MLP: q(5) -> 32 relu -> 16 relu -> 4
    float h1[32];
#pragma unroll
    for (int j = 0; j < 32; ++j) {
        float a = sd1[j];
#pragma unroll
        for (int k = 0; k < 5; ++k) a += q[k] * sD1[k * 32 + j];
        h1[j] = a > 0.f ? a : 0.f;
    }
    float h2[16];
#pragma unroll
    for (int j = 0; j < 16; ++j) {
        float a = sd2[j];
#pragma unroll
        for (int k = 0; k < 32; ++k) a += h1[k] * sD2[k * 16 + j];
        h2[j] = a > 0.f ? a : 0.f;
    }
    floatx4 o;
#pragma unroll
    for (int j = 0; j < 4; ++j) {
        float a = sd3[j];
#pragma unroll
        for (int k = 0; k < 16; ++k) a += h2[k] * sD3[k * 4 + j];
        o[j] = a;
    }
    *(floatx4*)(out + r * 4) = o;
}

// ---------------------------------------------------------------------------
extern "C" void kernel_launch(void* const* d_in, const int* in_sizes, int n_in,
                              void* d_out, int out_size, void* d_ws, size_t ws_size,
                              hipStream_t stream) {
    const float* state = (const float*)d_in[0];
    const float* W1 = (const float*)d_in[1];
    const float* b1 = (const float*)d_in[2];
    const float* W2 = (const float*)d_in[3];
    const float* b2 = (const float*)d_in[4];
    const float* W3 = (const float*)d_in[5];
    const float* b3 = (const float*)d_in[6];
    const float* qp = (const float*)d_in[7];
    const float* D1 = (const float*)d_in[8];
    const float* d1 = (const float*)d_in[9];
    const float* D2 = (const float*)d_in[10];
    const float* d2 = (const float*)d_in[11];
    const float* D3 = (const float*)d_in[12];
    const float* d3 = (const float*)d_in[13];
    float* out = (float*)d_out;

    const int B = in_sizes[0] / 252;     // 131072

    char* ws = (char*)d_ws;
    _Float16* w1f = (_Float16*)ws;                         // 64 frag-blocks = 64 KB
    _Float16* w2f = (_Float16*)(ws + 65536);               // 16 -> 16 KB
    _Float16* w3f = (_Float16*)(ws + 65536 + 16384);       // 2  -> 2 KB
    float*    enc = (float*)(ws + 65536 + 16384 + 2048);   // B*5 fp32

    prep_all<<<82, 64, 0, stream>>>(W1, W2, W3, w1f, w2f, w3f);
    front_kernel<<<B / 64, 256, 0, stream>>>(state, w1f, b1, w2f, b2, w3f, b3, enc);
    back_kernel<<<B / 256, 256, 0, stream>>>(enc, qp, D1, d1, D2, d2, D3, d3, out);
}